// Round 7
// baseline (201.835 us; speedup 1.0000x reference)
//
#include <hip/hip_runtime.h>

#define NB   4
#define NSEQ 4096
#define DK   64
#define NTOK (NB * NSEQ)

#define QK_SCALE 1.2011224087864498f   // sqrt(log2(e))

typedef __attribute__((ext_vector_type(8))) short short8;
typedef __attribute__((ext_vector_type(4))) float f32x4;

__device__ __forceinline__ float fast_exp2(float x) {
#if __has_builtin(__builtin_amdgcn_exp2f)
    return __builtin_amdgcn_exp2f(x);
#else
    return exp2f(x);
#endif
}

__device__ __forceinline__ unsigned short bf16_rne(float f) {
    unsigned u = __float_as_uint(f);
    u += 0x7fffu + ((u >> 16) & 1u);
    return (unsigned short)(u >> 16);
}

__device__ __forceinline__ short8 u4_to_s8(uint4 u) {
    union { uint4 u; short8 s; } c; c.u = u; return c.s;
}

// ---------------------------------------------------------------------------
// Kernel A: Qs/Ks = (x.wq/wk)*QK_SCALE, Vt[b][d][n] = bf16(x@Wv^T+bv)
// ---------------------------------------------------------------------------
__global__ __launch_bounds__(512) void qkv_kernel(
    const float* __restrict__ x, const float* __restrict__ Wv,
    const float* __restrict__ bv, const float* __restrict__ wq,
    const float* __restrict__ wk,
    float* __restrict__ Qs, float* __restrict__ Ks, unsigned short* __restrict__ Vt)
{
    __shared__ float x_lds[64 * 68];
    __shared__ float wvt[64 * 68];        // wvt[d*68+e] = Wv[e*64+d]
    __shared__ float wqk[128];
    __shared__ float bvl[64];
    __shared__ unsigned short vt_lds[64 * 72];   // [e][tok]

    const int t = threadIdx.x;
    const int tok0 = blockIdx.x * 64;

    #pragma unroll
    for (int r = 0; r < 2; ++r) {
        int f = t + 512 * r;
        int row = f >> 4, c4 = f & 15;
        float4 v = ((const float4*)(x + (size_t)(tok0 + row) * DK))[c4];
        *(float4*)&x_lds[row * 68 + c4 * 4] = v;
    }
    #pragma unroll
    for (int r = 0; r < 2; ++r) {
        int f = t + 512 * r;
        int e = f >> 4, c4 = f & 15;
        float4 v = ((const float4*)(Wv + e * DK))[c4];
        wvt[(c4 * 4 + 0) * 68 + e] = v.x;
        wvt[(c4 * 4 + 1) * 68 + e] = v.y;
        wvt[(c4 * 4 + 2) * 68 + e] = v.z;
        wvt[(c4 * 4 + 3) * 68 + e] = v.w;
    }
    if (t < 64) { wqk[t * 2] = wq[t]; wqk[t * 2 + 1] = wk[t]; bvl[t] = bv[t]; }
    __syncthreads();

    const int tok = t >> 3, oc = t & 7;
    const int e0 = oc * 8;
    float acc[8];
    #pragma unroll
    for (int ee = 0; ee < 8; ++ee) acc[ee] = bvl[e0 + ee];

    for (int d = 0; d < DK; d += 4) {
        float4 x4 = *(const float4*)&x_lds[tok * 68 + d];
        const float xs[4] = {x4.x, x4.y, x4.z, x4.w};
        #pragma unroll
        for (int dd = 0; dd < 4; ++dd) {
            float xv = xs[dd];
            const float4* wrow = (const float4*)&wvt[(d + dd) * 68 + e0];
            float4 wa = wrow[0], wb = wrow[1];
            acc[0] += xv * wa.x; acc[1] += xv * wa.y;
            acc[2] += xv * wa.z; acc[3] += xv * wa.w;
            acc[4] += xv * wb.x; acc[5] += xv * wb.y;
            acc[6] += xv * wb.z; acc[7] += xv * wb.w;
        }
    }
    #pragma unroll
    for (int k = 0; k < 8; ++k)
        vt_lds[(e0 + k) * 72 + tok] = bf16_rne(acc[k]);

    if (t < 128) {
        const int tk = t & 63;
        const int sel = (t >= 64);
        float a = 0.f;
        for (int d = 0; d < DK; ++d)
            a += x_lds[tk * 68 + d] * wqk[d * 2 + sel];
        (sel ? Ks : Qs)[tok0 + tk] = a * QK_SCALE;
    }
    __syncthreads();

    const int bb = tok0 >> 12, n0 = tok0 & 4095;
    {
        int d = t >> 3, c = t & 7;
        uint4 v = *(const uint4*)((const char*)vt_lds + d * 144 + c * 16);
        *(uint4*)(Vt + (size_t)(bb * 64 + d) * 4096 + n0 + c * 8) = v;
    }
}

// ---------------------------------------------------------------------------
// Kernel B: MFMA attention + residual + layernorm.
// MEASUREMENT VARIANT: whole per-block computation repeated `nrep` times
// (runtime arg; reps write identical outputs, barrier-separated) so one
// dispatch is long enough to surface in the rocprof top-5 with counters.
// Compute code is bit-identical to round 5.
// ---------------------------------------------------------------------------
extern __shared__ float smem[];

__global__ __launch_bounds__(1024, 4) void attn_kernel(
    const float* __restrict__ x,
    const float* __restrict__ Qsg, const float* __restrict__ Ksg,
    const unsigned short* __restrict__ Vt,
    const float* __restrict__ gamma, const float* __restrict__ beta,
    float* __restrict__ out, int nrep)
{
    float* k_lds = smem;                       // 4096 floats (16 KB)
    float* red   = smem + 4096;                // 8 slots x 64 rows x stride 68
    float* dred  = smem + 4096 + 8 * 64 * 68;  // 16 x 64

    const int t    = threadIdx.x;
    const int b    = blockIdx.x >> 6;
    const int i0   = (blockIdx.x & 63) << 6;
    const int je   = t >> 6;
    const int lane = t & 63;
    const int rit  = lane & 15;
    const int q    = lane >> 4;

    ((float4*)k_lds)[t] = ((const float4*)(Ksg + (size_t)b * 4096))[t];

    float Qr[4];
    #pragma unroll
    for (int rt = 0; rt < 4; ++rt)
        Qr[rt] = Qsg[b * 4096 + i0 + rt * 16 + rit];

    const short onebf = (short)0x3F80;
    const short8 vones = {onebf, onebf, onebf, onebf, onebf, onebf, onebf, onebf};

    const int jw = je * 256;
    const unsigned short* vb = Vt + (size_t)b * 64 * 4096 + (size_t)rit * 4096 + jw + q * 8;
    const float* kp = &k_lds[jw + q * 8];

    __syncthreads();   // k_lds ready

    for (int rep = 0; rep < nrep; ++rep) {

    f32x4 acc[4][4] = {};
    f32x4 accd[4] = {};

    #pragma unroll 2
    for (int s = 0; s < 8; ++s) {
        const unsigned short* vn = vb + s * 32;
        uint4 bu0 = *(const uint4*)(vn);
        uint4 bu1 = *(const uint4*)(vn + 16 * 4096);
        uint4 bu2 = *(const uint4*)(vn + 32 * 4096);
        uint4 bu3 = *(const uint4*)(vn + 48 * 4096);

        const float* kn = kp + s * 32;
        float4 ka = *(const float4*)(kn);
        float4 kb = *(const float4*)(kn + 4);
        float kv[8] = {ka.x, ka.y, ka.z, ka.w, kb.x, kb.y, kb.z, kb.w};

        short8 b0 = u4_to_s8(bu0), b1 = u4_to_s8(bu1);
        short8 b2 = u4_to_s8(bu2), b3 = u4_to_s8(bu3);

        #pragma unroll
        for (int rt = 0; rt < 4; ++rt) {
            float w0[8];
            #pragma unroll
            for (int jj = 0; jj < 8; ++jj) {
                float d0 = Qr[rt] - kv[jj];
                float g0 = fast_exp2(-d0 * d0);
                float p0 = __builtin_fmaf(g0, 3.2552083e-4f, 7.8125e-3f);
                p0 = __builtin_fmaf(g0, p0, 0.125f);
                w0[jj] = __builtin_fmaf(g0, p0, 1.0f);   // exp(exp(-(Q-K)^2)/8)
            }
            uint4 au;
            au.x = __builtin_amdgcn_perm(__float_as_uint(w0[1]), __float_as_uint(w0[0]), 0x07060302u);
            au.y = __builtin_amdgcn_perm(__float_as_uint(w0[3]), __float_as_uint(w0[2]), 0x07060302u);
            au.z = __builtin_amdgcn_perm(__float_as_uint(w0[5]), __float_as_uint(w0[4]), 0x07060302u);
            au.w = __builtin_amdgcn_perm(__float_as_uint(w0[7]), __float_as_uint(w0[6]), 0x07060302u);
            short8 a0 = u4_to_s8(au);

            acc[rt][0] = __builtin_amdgcn_mfma_f32_16x16x32_bf16(a0, b0, acc[rt][0], 0, 0, 0);
            acc[rt][1] = __builtin_amdgcn_mfma_f32_16x16x32_bf16(a0, b1, acc[rt][1], 0, 0, 0);
            acc[rt][2] = __builtin_amdgcn_mfma_f32_16x16x32_bf16(a0, b2, acc[rt][2], 0, 0, 0);
            acc[rt][3] = __builtin_amdgcn_mfma_f32_16x16x32_bf16(a0, b3, acc[rt][3], 0, 0, 0);
            accd[rt]   = __builtin_amdgcn_mfma_f32_16x16x32_bf16(a0, vones, accd[rt], 0, 0, 0);
        }
    }

    const int slot = je & 7;
    float* rbase = red + (size_t)slot * (64 * 68);
    if (je < 8) {
        #pragma unroll
        for (int rt = 0; rt < 4; ++rt)
            #pragma unroll
            for (int ct = 0; ct < 4; ++ct)
                #pragma unroll
                for (int rg = 0; rg < 4; ++rg)
                    rbase[(rt * 16 + q * 4 + rg) * 68 + ct * 16 + rit] = acc[rt][ct][rg];
    }
    if (rit == 0) {
        #pragma unroll
        for (int rt = 0; rt < 4; ++rt)
            #pragma unroll
            for (int rg = 0; rg < 4; ++rg)
                dred[je * 64 + rt * 16 + q * 4 + rg] = accd[rt][rg];
    }
    __syncthreads();
    if (je >= 8) {
        #pragma unroll
        for (int rt = 0; rt < 4; ++rt)
            #pragma unroll
            for (int ct = 0; ct < 4; ++ct)
                #pragma unroll
                for (int rg = 0; rg < 4; ++rg) {
                    int idx = (rt * 16 + q * 4 + rg) * 68 + ct * 16 + rit;
                    rbase[idx] += acc[rt][ct][rg];
                }
    }
    __syncthreads();

    const int row = t >> 4, cg = t & 15;
    float dsum = 0.f;
    #pragma unroll
    for (int sl = 0; sl < 16; ++sl) dsum += dred[sl * 64 + row];
    const float inv = 1.0f / dsum;
    const size_t rowg = (size_t)(b * 4096 + i0 + row);
    const float* xr = x + rowg * 64;

    float h[4], sm = 0.f, ss = 0.f;
    #pragma unroll
    for (int ct = 0; ct < 4; ++ct) {
        float num = 0.f;
        #pragma unroll
        for (int sl = 0; sl < 8; ++sl)
            num += red[(size_t)sl * (64 * 68) + row * 68 + ct * 16 + cg];
        h[ct] = num * inv + xr[ct * 16 + cg];
        sm += h[ct]; ss += h[ct] * h[ct];
    }
    #pragma unroll
    for (int m = 1; m < 16; m <<= 1) { sm += __shfl_xor(sm, m); ss += __shfl_xor(ss, m); }
    const float mu   = sm * 0.015625f;
    const float var  = ss * 0.015625f - mu * mu;
    const float rstd = rsqrtf(var + 1e-5f);

    float* orow = out + rowg * 64;
    #pragma unroll
    for (int ct = 0; ct < 4; ++ct)
        orow[ct * 16 + cg] = (h[ct] - mu) * rstd * gamma[ct * 16 + cg] + beta[ct * 16 + cg];

    __syncthreads();   // rep isolation: epilogue reads done before next rep's writes
    }
}

// ---------------------------------------------------------------------------
extern "C" void kernel_launch(void* const* d_in, const int* in_sizes, int n_in,
                              void* d_out, int out_size, void* d_ws, size_t ws_size,
                              hipStream_t stream)
{
    const float* x     = (const float*)d_in[0];
    const float* Wv    = (const float*)d_in[1];
    const float* bv    = (const float*)d_in[2];
    const float* wq    = (const float*)d_in[3];
    const float* wk    = (const float*)d_in[4];
    const float* gamma = (const float*)d_in[5];
    const float* beta  = (const float*)d_in[6];
    float* out = (float*)d_out;

    float* Qs = (float*)d_ws;
    float* Ks = Qs + NTOK;
    unsigned short* Vt = (unsigned short*)(Ks + NTOK);

    const int attn_lds = 4096 * 4 + 8 * 64 * 68 * 4 + 16 * 64 * 4;
    hipFuncSetAttribute((const void*)attn_kernel,
                        hipFuncAttributeMaxDynamicSharedMemorySize, attn_lds);

    qkv_kernel<<<dim3(NTOK / 64), dim3(512), 0, stream>>>(x, Wv, bv, wq, wk, Qs, Ks, Vt);
    attn_kernel<<<dim3(NB * (NSEQ / 64)), dim3(1024), attn_lds, stream>>>(
        x, Qs, Ks, Vt, gamma, beta, out, 4);
}

// Round 8
// 105.218 us; speedup vs baseline: 1.9183x; 1.9183x over previous
//
#include <hip/hip_runtime.h>

#define NB   4
#define NSEQ 4096
#define DK   64
#define NTOK (NB * NSEQ)

#define QK_SCALE 1.2011224087864498f   // sqrt(log2(e))

typedef __attribute__((ext_vector_type(8))) short short8;
typedef __attribute__((ext_vector_type(4))) float f32x4;

__device__ __forceinline__ float fast_exp2(float x) {
#if __has_builtin(__builtin_amdgcn_exp2f)
    return __builtin_amdgcn_exp2f(x);
#else
    return exp2f(x);
#endif
}

__device__ __forceinline__ unsigned short bf16_rne(float f) {
    unsigned u = __float_as_uint(f);
    u += 0x7fffu + ((u >> 16) & 1u);
    return (unsigned short)(u >> 16);
}

__device__ __forceinline__ short8 u4_to_s8(uint4 u) {
    union { uint4 u; short8 s; } c; c.u = u; return c.s;
}

// ---------------------------------------------------------------------------
// Kernel A: Qs/Ks = (x.wq/wk)*QK_SCALE, Vt[b][d][n] = bf16(x@Wv^T+bv)
// ---------------------------------------------------------------------------
__global__ __launch_bounds__(512) void qkv_kernel(
    const float* __restrict__ x, const float* __restrict__ Wv,
    const float* __restrict__ bv, const float* __restrict__ wq,
    const float* __restrict__ wk,
    float* __restrict__ Qs, float* __restrict__ Ks, unsigned short* __restrict__ Vt)
{
    __shared__ float x_lds[64 * 68];
    __shared__ float wvt[64 * 68];        // wvt[d*68+e] = Wv[e*64+d]
    __shared__ float wqk[128];
    __shared__ float bvl[64];
    __shared__ unsigned short vt_lds[64 * 72];   // [e][tok]

    const int t = threadIdx.x;
    const int tok0 = blockIdx.x * 64;

    #pragma unroll
    for (int r = 0; r < 2; ++r) {
        int f = t + 512 * r;
        int row = f >> 4, c4 = f & 15;
        float4 v = ((const float4*)(x + (size_t)(tok0 + row) * DK))[c4];
        *(float4*)&x_lds[row * 68 + c4 * 4] = v;
    }
    #pragma unroll
    for (int r = 0; r < 2; ++r) {
        int f = t + 512 * r;
        int e = f >> 4, c4 = f & 15;
        float4 v = ((const float4*)(Wv + e * DK))[c4];
        wvt[(c4 * 4 + 0) * 68 + e] = v.x;
        wvt[(c4 * 4 + 1) * 68 + e] = v.y;
        wvt[(c4 * 4 + 2) * 68 + e] = v.z;
        wvt[(c4 * 4 + 3) * 68 + e] = v.w;
    }
    if (t < 64) { wqk[t * 2] = wq[t]; wqk[t * 2 + 1] = wk[t]; bvl[t] = bv[t]; }
    __syncthreads();

    const int tok = t >> 3, oc = t & 7;
    const int e0 = oc * 8;
    float acc[8];
    #pragma unroll
    for (int ee = 0; ee < 8; ++ee) acc[ee] = bvl[e0 + ee];

    for (int d = 0; d < DK; d += 4) {
        float4 x4 = *(const float4*)&x_lds[tok * 68 + d];
        const float xs[4] = {x4.x, x4.y, x4.z, x4.w};
        #pragma unroll
        for (int dd = 0; dd < 4; ++dd) {
            float xv = xs[dd];
            const float4* wrow = (const float4*)&wvt[(d + dd) * 68 + e0];
            float4 wa = wrow[0], wb = wrow[1];
            acc[0] += xv * wa.x; acc[1] += xv * wa.y;
            acc[2] += xv * wa.z; acc[3] += xv * wa.w;
            acc[4] += xv * wb.x; acc[5] += xv * wb.y;
            acc[6] += xv * wb.z; acc[7] += xv * wb.w;
        }
    }
    #pragma unroll
    for (int k = 0; k < 8; ++k)
        vt_lds[(e0 + k) * 72 + tok] = bf16_rne(acc[k]);

    if (t < 128) {
        const int tk = t & 63;
        const int sel = (t >= 64);
        float a = 0.f;
        for (int d = 0; d < DK; ++d)
            a += x_lds[tk * 68 + d] * wqk[d * 2 + sel];
        (sel ? Ks : Qs)[tok0 + tk] = a * QK_SCALE;
    }
    __syncthreads();

    const int bb = tok0 >> 12, n0 = tok0 & 4095;
    {
        int d = t >> 3, c = t & 7;
        uint4 v = *(const uint4*)((const char*)vt_lds + d * 144 + c * 16);
        *(uint4*)(Vt + (size_t)(bb * 64 + d) * 4096 + n0 + c * 8) = v;
    }
}

// ---------------------------------------------------------------------------
// Kernel B: MFMA attention + residual + layernorm.
// 256 blocks x 1024 threads (16 waves = 4/SIMD, 1 block/CU via LDS).
// XCD swizzle: batch b owns XCD pair {2b,2b+1} so each XCD's L2 working set
// is one batch's Vt (2 MB) -> B loads are L2 hits.
// Wave (rgrp = w>>3: 32 rows, je = w&7: 512-j slice): acc[2][4]+accd[2] =
// 40 accum regs -> no spill under the 128-reg/wave 16-wave-residency budget.
// Denominator via ones-MFMA. Coalesced float4 epilogue (full-line stores).
// ---------------------------------------------------------------------------
extern __shared__ float smem[];

__global__ __launch_bounds__(1024, 4) void attn_kernel(
    const float* __restrict__ x,
    const float* __restrict__ Qsg, const float* __restrict__ Ksg,
    const unsigned short* __restrict__ Vt,
    const float* __restrict__ gamma, const float* __restrict__ beta,
    float* __restrict__ out, int nrep)
{
    float* k_lds = smem;                       // 4096 floats (16 KB)
    float* red   = smem + 4096;                // 8 slots x 64 rows x stride 68 (139.3 KB)
    float* dred  = smem + 4096 + 8 * 64 * 68;  // 8 x 64 (2 KB)

    const int t    = threadIdx.x;
    const int B    = blockIdx.x;
    const int b    = (B & 7) >> 1;                         // batch <- XCD pair
    const int i0   = (((B >> 3) << 1) | (B & 1)) << 6;     // i-tile 0..63
    const int w    = t >> 6;
    const int lane = t & 63;
    const int rit  = lane & 15;
    const int q    = lane >> 4;
    const int rgrp = w >> 3;          // 0..1: 32-row group
    const int je   = w & 7;           // 0..7: 512-j slice

    ((float4*)k_lds)[t] = ((const float4*)(Ksg + (size_t)b * 4096))[t];

    const float Qs0 = Qsg[b * 4096 + i0 + rgrp * 32 + rit];
    const float Qs1 = Qsg[b * 4096 + i0 + rgrp * 32 + 16 + rit];

    const short onebf = (short)0x3F80;
    const short8 vones = {onebf, onebf, onebf, onebf, onebf, onebf, onebf, onebf};

    const int jw = je * 512;
    const unsigned short* vb = Vt + (size_t)b * 64 * 4096 + (size_t)rit * 4096 + jw + q * 8;
    const float* kp = &k_lds[jw + q * 8];

    __syncthreads();   // k_lds ready

    for (int rep = 0; rep < nrep; ++rep) {

    f32x4 acc[2][4] = {};
    f32x4 accd[2] = {};

    #pragma unroll 2
    for (int s = 0; s < 16; ++s) {
        const unsigned short* vn = vb + s * 32;
        uint4 bu0 = *(const uint4*)(vn);
        uint4 bu1 = *(const uint4*)(vn + 16 * 4096);
        uint4 bu2 = *(const uint4*)(vn + 32 * 4096);
        uint4 bu3 = *(const uint4*)(vn + 48 * 4096);

        const float* kn = kp + s * 32;
        float4 ka = *(const float4*)(kn);
        float4 kb = *(const float4*)(kn + 4);
        float kv[8] = {ka.x, ka.y, ka.z, ka.w, kb.x, kb.y, kb.z, kb.w};

        float w0[8], w1[8];
        #pragma unroll
        for (int jj = 0; jj < 8; ++jj) {
            float d0 = Qs0 - kv[jj];
            float g0 = fast_exp2(-d0 * d0);
            float p0 = __builtin_fmaf(g0, 3.2552083e-4f, 7.8125e-3f);
            p0 = __builtin_fmaf(g0, p0, 0.125f);
            w0[jj] = __builtin_fmaf(g0, p0, 1.0f);   // exp(exp(-(Q-K)^2)/8)
            float d1 = Qs1 - kv[jj];
            float g1 = fast_exp2(-d1 * d1);
            float p1 = __builtin_fmaf(g1, 3.2552083e-4f, 7.8125e-3f);
            p1 = __builtin_fmaf(g1, p1, 0.125f);
            w1[jj] = __builtin_fmaf(g1, p1, 1.0f);
        }
        uint4 au0, au1;
        au0.x = __builtin_amdgcn_perm(__float_as_uint(w0[1]), __float_as_uint(w0[0]), 0x07060302u);
        au0.y = __builtin_amdgcn_perm(__float_as_uint(w0[3]), __float_as_uint(w0[2]), 0x07060302u);
        au0.z = __builtin_amdgcn_perm(__float_as_uint(w0[5]), __float_as_uint(w0[4]), 0x07060302u);
        au0.w = __builtin_amdgcn_perm(__float_as_uint(w0[7]), __float_as_uint(w0[6]), 0x07060302u);
        au1.x = __builtin_amdgcn_perm(__float_as_uint(w1[1]), __float_as_uint(w1[0]), 0x07060302u);
        au1.y = __builtin_amdgcn_perm(__float_as_uint(w1[3]), __float_as_uint(w1[2]), 0x07060302u);
        au1.z = __builtin_amdgcn_perm(__float_as_uint(w1[5]), __float_as_uint(w1[4]), 0x07060302u);
        au1.w = __builtin_amdgcn_perm(__float_as_uint(w1[7]), __float_as_uint(w1[6]), 0x07060302u);
        short8 a0 = u4_to_s8(au0);
        short8 a1 = u4_to_s8(au1);

        short8 b0 = u4_to_s8(bu0), b1 = u4_to_s8(bu1);
        short8 b2 = u4_to_s8(bu2), b3 = u4_to_s8(bu3);
        acc[0][0] = __builtin_amdgcn_mfma_f32_16x16x32_bf16(a0, b0, acc[0][0], 0, 0, 0);
        acc[0][1] = __builtin_amdgcn_mfma_f32_16x16x32_bf16(a0, b1, acc[0][1], 0, 0, 0);
        acc[0][2] = __builtin_amdgcn_mfma_f32_16x16x32_bf16(a0, b2, acc[0][2], 0, 0, 0);
        acc[0][3] = __builtin_amdgcn_mfma_f32_16x16x32_bf16(a0, b3, acc[0][3], 0, 0, 0);
        acc[1][0] = __builtin_amdgcn_mfma_f32_16x16x32_bf16(a1, b0, acc[1][0], 0, 0, 0);
        acc[1][1] = __builtin_amdgcn_mfma_f32_16x16x32_bf16(a1, b1, acc[1][1], 0, 0, 0);
        acc[1][2] = __builtin_amdgcn_mfma_f32_16x16x32_bf16(a1, b2, acc[1][2], 0, 0, 0);
        acc[1][3] = __builtin_amdgcn_mfma_f32_16x16x32_bf16(a1, b3, acc[1][3], 0, 0, 0);
        accd[0]   = __builtin_amdgcn_mfma_f32_16x16x32_bf16(a0, vones, accd[0], 0, 0, 0);
        accd[1]   = __builtin_amdgcn_mfma_f32_16x16x32_bf16(a1, vones, accd[1], 0, 0, 0);
    }

    // ---- write partials; C/D layout: col=rit, row=q*4+rg. 16 waves disjoint.
    {
        float* rbase = red + (size_t)je * (64 * 68);
        #pragma unroll
        for (int rt = 0; rt < 2; ++rt)
            #pragma unroll
            for (int ct = 0; ct < 4; ++ct)
                #pragma unroll
                for (int rg = 0; rg < 4; ++rg)
                    rbase[(rgrp * 32 + rt * 16 + q * 4 + rg) * 68 + ct * 16 + rit]
                        = acc[rt][ct][rg];
        if (rit == 0) {
            #pragma unroll
            for (int rt = 0; rt < 2; ++rt)
                #pragma unroll
                for (int rg = 0; rg < 4; ++rg)
                    dred[je * 64 + rgrp * 32 + rt * 16 + q * 4 + rg] = accd[rt][rg];
        }
    }
    __syncthreads();

    // ---- coalesced epilogue: thread = (row, 4 consecutive cols)
    {
        const int row = t >> 4, cg = t & 15, c0 = cg * 4;
        float dsum = 0.f;
        #pragma unroll
        for (int sl = 0; sl < 8; ++sl) dsum += dred[sl * 64 + row];
        const float inv = 1.0f / dsum;
        const size_t rowg = (size_t)(b * 4096 + i0 + row);

        float4 num = make_float4(0.f, 0.f, 0.f, 0.f);
        #pragma unroll
        for (int sl = 0; sl < 8; ++sl) {
            float4 r4 = *(const float4*)&red[(size_t)sl * (64 * 68) + row * 68 + c0];
            num.x += r4.x; num.y += r4.y; num.z += r4.z; num.w += r4.w;
        }
        const float4 x4 = *(const float4*)(x + rowg * 64 + c0);
        float4 h;
        h.x = num.x * inv + x4.x;
        h.y = num.y * inv + x4.y;
        h.z = num.z * inv + x4.z;
        h.w = num.w * inv + x4.w;

        float sm = h.x + h.y + h.z + h.w;
        float ss = h.x * h.x + h.y * h.y + h.z * h.z + h.w * h.w;
        #pragma unroll
        for (int m = 1; m < 16; m <<= 1) { sm += __shfl_xor(sm, m); ss += __shfl_xor(ss, m); }
        const float mu   = sm * 0.015625f;
        const float var  = ss * 0.015625f - mu * mu;
        const float rstd = rsqrtf(var + 1e-5f);

        const float4 g4 = *(const float4*)(gamma + c0);
        const float4 b4 = *(const float4*)(beta + c0);
        float4 o;
        o.x = (h.x - mu) * rstd * g4.x + b4.x;
        o.y = (h.y - mu) * rstd * g4.y + b4.y;
        o.z = (h.z - mu) * rstd * g4.z + b4.z;
        o.w = (h.w - mu) * rstd * g4.w + b4.w;
        *(float4*)(out + rowg * 64 + c0) = o;
    }
    __syncthreads();   // rep isolation
    }
}

// ---------------------------------------------------------------------------
extern "C" void kernel_launch(void* const* d_in, const int* in_sizes, int n_in,
                              void* d_out, int out_size, void* d_ws, size_t ws_size,
                              hipStream_t stream)
{
    const float* x     = (const float*)d_in[0];
    const float* Wv    = (const float*)d_in[1];
    const float* bv    = (const float*)d_in[2];
    const float* wq    = (const float*)d_in[3];
    const float* wk    = (const float*)d_in[4];
    const float* gamma = (const float*)d_in[5];
    const float* beta  = (const float*)d_in[6];
    float* out = (float*)d_out;

    float* Qs = (float*)d_ws;
    float* Ks = Qs + NTOK;
    unsigned short* Vt = (unsigned short*)(Ks + NTOK);

    // dynamic LDS: k 16384 + red 139264 + dred 2048 = 157696 B
    const int attn_lds = 4096 * 4 + 8 * 64 * 68 * 4 + 8 * 64 * 4;
    hipFuncSetAttribute((const void*)attn_kernel,
                        hipFuncAttributeMaxDynamicSharedMemorySize, attn_lds);

    qkv_kernel<<<dim3(NTOK / 64), dim3(512), 0, stream>>>(x, Wv, bv, wq, wk, Qs, Ks, Vt);
    attn_kernel<<<dim3(NB * (NSEQ / 64)), dim3(1024), attn_lds, stream>>>(
        x, Qs, Ks, Vt, gamma, beta, out, 1);
}

// Round 9
// 95.571 us; speedup vs baseline: 2.1119x; 1.1009x over previous
//
#include <hip/hip_runtime.h>

#define NB   4
#define NSEQ 4096
#define DK   64
#define NTOK (NB * NSEQ)

#define QK_SCALE 1.2011224087864498f   // sqrt(log2(e))

typedef __attribute__((ext_vector_type(8))) short short8;
typedef __attribute__((ext_vector_type(4))) float f32x4;

__device__ __forceinline__ float fast_exp2(float x) {
#if __has_builtin(__builtin_amdgcn_exp2f)
    return __builtin_amdgcn_exp2f(x);
#else
    return exp2f(x);
#endif
}

__device__ __forceinline__ unsigned short bf16_rne(float f) {
    unsigned u = __float_as_uint(f);
    u += 0x7fffu + ((u >> 16) & 1u);
    return (unsigned short)(u >> 16);
}

__device__ __forceinline__ short8 u4_to_s8(uint4 u) {
    union { uint4 u; short8 s; } c; c.u = u; return c.s;
}

#define AS3U(p) ((__attribute__((address_space(3))) unsigned int*)(p))
#define AS1U(p) ((const __attribute__((address_space(1))) unsigned int*)(p))

// ---------------------------------------------------------------------------
// Kernel A: Qs/Ks = (x.wq/wk)*QK_SCALE, Vt[b][d][n] = bf16(x@Wv^T+bv)
// ---------------------------------------------------------------------------
__global__ __launch_bounds__(512) void qkv_kernel(
    const float* __restrict__ x, const float* __restrict__ Wv,
    const float* __restrict__ bv, const float* __restrict__ wq,
    const float* __restrict__ wk,
    float* __restrict__ Qs, float* __restrict__ Ks, unsigned short* __restrict__ Vt)
{
    __shared__ float x_lds[64 * 68];
    __shared__ float wvt[64 * 68];        // wvt[d*68+e] = Wv[e*64+d]
    __shared__ float wqk[128];
    __shared__ float bvl[64];
    __shared__ unsigned short vt_lds[64 * 72];   // [e][tok]

    const int t = threadIdx.x;
    const int tok0 = blockIdx.x * 64;

    #pragma unroll
    for (int r = 0; r < 2; ++r) {
        int f = t + 512 * r;
        int row = f >> 4, c4 = f & 15;
        float4 v = ((const float4*)(x + (size_t)(tok0 + row) * DK))[c4];
        *(float4*)&x_lds[row * 68 + c4 * 4] = v;
    }
    #pragma unroll
    for (int r = 0; r < 2; ++r) {
        int f = t + 512 * r;
        int e = f >> 4, c4 = f & 15;
        float4 v = ((const float4*)(Wv + e * DK))[c4];
        wvt[(c4 * 4 + 0) * 68 + e] = v.x;
        wvt[(c4 * 4 + 1) * 68 + e] = v.y;
        wvt[(c4 * 4 + 2) * 68 + e] = v.z;
        wvt[(c4 * 4 + 3) * 68 + e] = v.w;
    }
    if (t < 64) { wqk[t * 2] = wq[t]; wqk[t * 2 + 1] = wk[t]; bvl[t] = bv[t]; }
    __syncthreads();

    const int tok = t >> 3, oc = t & 7;
    const int e0 = oc * 8;
    float acc[8];
    #pragma unroll
    for (int ee = 0; ee < 8; ++ee) acc[ee] = bvl[e0 + ee];

    for (int d = 0; d < DK; d += 4) {
        float4 x4 = *(const float4*)&x_lds[tok * 68 + d];
        const float xs[4] = {x4.x, x4.y, x4.z, x4.w};
        #pragma unroll
        for (int dd = 0; dd < 4; ++dd) {
            float xv = xs[dd];
            const float4* wrow = (const float4*)&wvt[(d + dd) * 68 + e0];
            float4 wa = wrow[0], wb = wrow[1];
            acc[0] += xv * wa.x; acc[1] += xv * wa.y;
            acc[2] += xv * wa.z; acc[3] += xv * wa.w;
            acc[4] += xv * wb.x; acc[5] += xv * wb.y;
            acc[6] += xv * wb.z; acc[7] += xv * wb.w;
        }
    }
    #pragma unroll
    for (int k = 0; k < 8; ++k)
        vt_lds[(e0 + k) * 72 + tok] = bf16_rne(acc[k]);

    if (t < 128) {
        const int tk = t & 63;
        const int sel = (t >= 64);
        float a = 0.f;
        for (int d = 0; d < DK; ++d)
            a += x_lds[tk * 68 + d] * wqk[d * 2 + sel];
        (sel ? Ks : Qs)[tok0 + tk] = a * QK_SCALE;
    }
    __syncthreads();

    const int bb = tok0 >> 12, n0 = tok0 & 4095;
    {
        int d = t >> 3, c = t & 7;
        uint4 v = *(const uint4*)((const char*)vt_lds + d * 144 + c * 16);
        *(uint4*)(Vt + (size_t)(bb * 64 + d) * 4096 + n0 + c * 8) = v;
    }
}

// ---------------------------------------------------------------------------
// Kernel B: MFMA attention + residual + layernorm.
// 256 blocks x 1024 threads (16 waves, 4/SIMD). XCD swizzle for L2 locality.
// V staged to LDS via global_load_lds (coalesced DMA, 32x fewer L2 requests
// than direct scattered B-fragment loads). Double-buffered 64KB rounds; the
// staging buffers reuse the red-partials LDS region (needed only post-loop).
// Rounds: r in 0..7, j-window [r*512, r*512+512); wave (rgrp,js) computes
// js's 64-j piece (2 MFMA k-steps) for 32 rows. Denominator via ones-MFMA.
// LDS (floats): [0,4096) k | [4096,38912) union{Vstage 2x64x520 bf16, red 8x64x68} | [38912,39424) dred
// ---------------------------------------------------------------------------
extern __shared__ float smem[];

__global__ __launch_bounds__(1024, 4) void attn_kernel(
    const float* __restrict__ x,
    const float* __restrict__ Qsg, const float* __restrict__ Ksg,
    const unsigned short* __restrict__ Vt,
    const float* __restrict__ gamma, const float* __restrict__ beta,
    float* __restrict__ out, int nrep)
{
    float* k_lds = smem;                          // 4096 floats
    unsigned short* vs = (unsigned short*)(smem + 4096);   // 2 x 64 x 520 bf16
    float* red   = smem + 4096;                   // 8 slots x 64 rows x 68 (post-loop reuse)
    float* dred  = smem + 4096 + 8 * 64 * 68;     // 8 x 64

    const int t    = threadIdx.x;
    const int B    = blockIdx.x;
    const int b    = (B & 7) >> 1;                         // batch <- XCD pair
    const int i0   = (((B >> 3) << 1) | (B & 1)) << 6;     // i-tile
    const int w    = t >> 6;
    const int lane = t & 63;
    const int rit  = lane & 15;
    const int q    = lane >> 4;
    const int rgrp = w >> 3;          // 0..1: 32-row group
    const int js   = w & 7;           // 0..7: 64-j piece within each round

    ((float4*)k_lds)[t] = ((const float4*)(Ksg + (size_t)b * 4096))[t];

    const float Qs0 = Qsg[b * 4096 + i0 + rgrp * 32 + rit];
    const float Qs1 = Qsg[b * 4096 + i0 + rgrp * 32 + 16 + rit];

    const short onebf = (short)0x3F80;
    const short8 vones = {onebf, onebf, onebf, onebf, onebf, onebf, onebf, onebf};

    const unsigned short* Vtb0 = Vt + (size_t)b * 64 * 4096;

    for (int rep = 0; rep < nrep; ++rep) {

    f32x4 acc[2][4] = {};
    f32x4 accd[2] = {};

    // ---- prologue: stage round 0 into buf 0 (4 coalesced DMA rows per wave)
    #pragma unroll
    for (int i = 0; i < 4; ++i) {
        const int d = w + 16 * i;
        const unsigned short* g = Vtb0 + (size_t)d * 4096 + lane * 8;
        unsigned short* l = vs + d * 520;          // wave-uniform base; DMA adds lane*16
#if __has_builtin(__builtin_amdgcn_global_load_lds)
        __builtin_amdgcn_global_load_lds(AS1U(g), AS3U(l), 16, 0, 0);
#else
        *(uint4*)(l + lane * 8) = *(const uint4*)g;
#endif
    }
    __syncthreads();   // k_lds + buf0 ready

    for (int r = 0; r < 8; ++r) {
        const int bf = r & 1;
        // ---- issue next round's DMA early (drained by end-of-round barrier)
        if (r < 7) {
            const int jw = (r + 1) * 512;
            #pragma unroll
            for (int i = 0; i < 4; ++i) {
                const int d = w + 16 * i;
                const unsigned short* g = Vtb0 + (size_t)d * 4096 + jw + lane * 8;
                unsigned short* l = vs + (bf ^ 1) * 33280 + d * 520;
#if __has_builtin(__builtin_amdgcn_global_load_lds)
                __builtin_amdgcn_global_load_lds(AS1U(g), AS3U(l), 16, 0, 0);
#else
                *(uint4*)(l + lane * 8) = *(const uint4*)g;
#endif
            }
        }

        // ---- compute: 2 MFMA k-steps from buf bf
        #pragma unroll
        for (int sl = 0; sl < 2; ++sl) {
            const int jloc = js * 64 + sl * 32;            // j within round window
            const unsigned short* vf = vs + bf * 33280 + rit * 520 + jloc + q * 8;
            uint4 bu0 = *(const uint4*)(vf);
            uint4 bu1 = *(const uint4*)(vf + 16 * 520);
            uint4 bu2 = *(const uint4*)(vf + 32 * 520);
            uint4 bu3 = *(const uint4*)(vf + 48 * 520);

            const float* kn = k_lds + r * 512 + jloc + q * 8;
            float4 ka = *(const float4*)(kn);
            float4 kb = *(const float4*)(kn + 4);
            float kv[8] = {ka.x, ka.y, ka.z, ka.w, kb.x, kb.y, kb.z, kb.w};

            float w0[8], w1[8];
            #pragma unroll
            for (int jj = 0; jj < 8; ++jj) {
                float d0 = Qs0 - kv[jj];
                float g0 = fast_exp2(-d0 * d0);
                float p0 = __builtin_fmaf(g0, 3.2552083e-4f, 7.8125e-3f);
                p0 = __builtin_fmaf(g0, p0, 0.125f);
                w0[jj] = __builtin_fmaf(g0, p0, 1.0f);   // exp(exp(-(Q-K)^2)/8)
                float d1 = Qs1 - kv[jj];
                float g1 = fast_exp2(-d1 * d1);
                float p1 = __builtin_fmaf(g1, 3.2552083e-4f, 7.8125e-3f);
                p1 = __builtin_fmaf(g1, p1, 0.125f);
                w1[jj] = __builtin_fmaf(g1, p1, 1.0f);
            }
            uint4 au0, au1;
            au0.x = __builtin_amdgcn_perm(__float_as_uint(w0[1]), __float_as_uint(w0[0]), 0x07060302u);
            au0.y = __builtin_amdgcn_perm(__float_as_uint(w0[3]), __float_as_uint(w0[2]), 0x07060302u);
            au0.z = __builtin_amdgcn_perm(__float_as_uint(w0[5]), __float_as_uint(w0[4]), 0x07060302u);
            au0.w = __builtin_amdgcn_perm(__float_as_uint(w0[7]), __float_as_uint(w0[6]), 0x07060302u);
            au1.x = __builtin_amdgcn_perm(__float_as_uint(w1[1]), __float_as_uint(w1[0]), 0x07060302u);
            au1.y = __builtin_amdgcn_perm(__float_as_uint(w1[3]), __float_as_uint(w1[2]), 0x07060302u);
            au1.z = __builtin_amdgcn_perm(__float_as_uint(w1[5]), __float_as_uint(w1[4]), 0x07060302u);
            au1.w = __builtin_amdgcn_perm(__float_as_uint(w1[7]), __float_as_uint(w1[6]), 0x07060302u);
            short8 a0 = u4_to_s8(au0);
            short8 a1 = u4_to_s8(au1);

            short8 b0 = u4_to_s8(bu0), b1 = u4_to_s8(bu1);
            short8 b2 = u4_to_s8(bu2), b3 = u4_to_s8(bu3);
            acc[0][0] = __builtin_amdgcn_mfma_f32_16x16x32_bf16(a0, b0, acc[0][0], 0, 0, 0);
            acc[0][1] = __builtin_amdgcn_mfma_f32_16x16x32_bf16(a0, b1, acc[0][1], 0, 0, 0);
            acc[0][2] = __builtin_amdgcn_mfma_f32_16x16x32_bf16(a0, b2, acc[0][2], 0, 0, 0);
            acc[0][3] = __builtin_amdgcn_mfma_f32_16x16x32_bf16(a0, b3, acc[0][3], 0, 0, 0);
            acc[1][0] = __builtin_amdgcn_mfma_f32_16x16x32_bf16(a1, b0, acc[1][0], 0, 0, 0);
            acc[1][1] = __builtin_amdgcn_mfma_f32_16x16x32_bf16(a1, b1, acc[1][1], 0, 0, 0);
            acc[1][2] = __builtin_amdgcn_mfma_f32_16x16x32_bf16(a1, b2, acc[1][2], 0, 0, 0);
            acc[1][3] = __builtin_amdgcn_mfma_f32_16x16x32_bf16(a1, b3, acc[1][3], 0, 0, 0);
            accd[0]   = __builtin_amdgcn_mfma_f32_16x16x32_bf16(a0, vones, accd[0], 0, 0, 0);
            accd[1]   = __builtin_amdgcn_mfma_f32_16x16x32_bf16(a1, vones, accd[1], 0, 0, 0);
        }
        __syncthreads();   // publishes buf bf^1 (DMA drained), protects buf reuse
    }

    // ---- write partials into red (reuses staging region; all reads done)
    {
        float* rbase = red + (size_t)js * (64 * 68);
        #pragma unroll
        for (int rt = 0; rt < 2; ++rt)
            #pragma unroll
            for (int ct = 0; ct < 4; ++ct)
                #pragma unroll
                for (int rg = 0; rg < 4; ++rg)
                    rbase[(rgrp * 32 + rt * 16 + q * 4 + rg) * 68 + ct * 16 + rit]
                        = acc[rt][ct][rg];
        if (rit == 0) {
            #pragma unroll
            for (int rt = 0; rt < 2; ++rt)
                #pragma unroll
                for (int rg = 0; rg < 4; ++rg)
                    dred[js * 64 + rgrp * 32 + rt * 16 + q * 4 + rg] = accd[rt][rg];
        }
    }
    __syncthreads();

    // ---- coalesced epilogue: thread = (row, 4 consecutive cols)
    {
        const int row = t >> 4, cg = t & 15, c0 = cg * 4;
        float dsum = 0.f;
        #pragma unroll
        for (int sl = 0; sl < 8; ++sl) dsum += dred[sl * 64 + row];
        const float inv = 1.0f / dsum;
        const size_t rowg = (size_t)(b * 4096 + i0 + row);

        float4 num = make_float4(0.f, 0.f, 0.f, 0.f);
        #pragma unroll
        for (int sl = 0; sl < 8; ++sl) {
            float4 r4 = *(const float4*)&red[(size_t)sl * (64 * 68) + row * 68 + c0];
            num.x += r4.x; num.y += r4.y; num.z += r4.z; num.w += r4.w;
        }
        const float4 x4 = *(const float4*)(x + rowg * 64 + c0);
        float4 h;
        h.x = num.x * inv + x4.x;
        h.y = num.y * inv + x4.y;
        h.z = num.z * inv + x4.z;
        h.w = num.w * inv + x4.w;

        float sm = h.x + h.y + h.z + h.w;
        float ss = h.x * h.x + h.y * h.y + h.z * h.z + h.w * h.w;
        #pragma unroll
        for (int m = 1; m < 16; m <<= 1) { sm += __shfl_xor(sm, m); ss += __shfl_xor(ss, m); }
        const float mu   = sm * 0.015625f;
        const float var  = ss * 0.015625f - mu * mu;
        const float rstd = rsqrtf(var + 1e-5f);

        const float4 g4 = *(const float4*)(gamma + c0);
        const float4 b4 = *(const float4*)(beta + c0);
        float4 o;
        o.x = (h.x - mu) * rstd * g4.x + b4.x;
        o.y = (h.y - mu) * rstd * g4.y + b4.y;
        o.z = (h.z - mu) * rstd * g4.z + b4.z;
        o.w = (h.w - mu) * rstd * g4.w + b4.w;
        *(float4*)(out + rowg * 64 + c0) = o;
    }
    __syncthreads();   // rep isolation (epilogue reads done before next rep stages)
    }
}

// ---------------------------------------------------------------------------
extern "C" void kernel_launch(void* const* d_in, const int* in_sizes, int n_in,
                              void* d_out, int out_size, void* d_ws, size_t ws_size,
                              hipStream_t stream)
{
    const float* x     = (const float*)d_in[0];
    const float* Wv    = (const float*)d_in[1];
    const float* bv    = (const float*)d_in[2];
    const float* wq    = (const float*)d_in[3];
    const float* wk    = (const float*)d_in[4];
    const float* gamma = (const float*)d_in[5];
    const float* beta  = (const float*)d_in[6];
    float* out = (float*)d_out;

    float* Qs = (float*)d_ws;
    float* Ks = Qs + NTOK;
    unsigned short* Vt = (unsigned short*)(Ks + NTOK);

    // dynamic LDS: k 16384 + union(red 139264 / Vstage 133120) + dred 2048 = 157696 B
    const int attn_lds = 4096 * 4 + 8 * 64 * 68 * 4 + 8 * 64 * 4;
    hipFuncSetAttribute((const void*)attn_kernel,
                        hipFuncAttributeMaxDynamicSharedMemorySize, attn_lds);

    qkv_kernel<<<dim3(NTOK / 64), dim3(512), 0, stream>>>(x, Wv, bv, wq, wk, Qs, Ks, Vt);
    attn_kernel<<<dim3(NB * (NSEQ / 64)), dim3(1024), attn_lds, stream>>>(
        x, Qs, Ks, Vt, gamma, beta, out, 1);
}

// Round 10
// 94.850 us; speedup vs baseline: 2.1279x; 1.0076x over previous
//
#include <hip/hip_runtime.h>

#define NB   4
#define NSEQ 4096
#define DK   64
#define NTOK (NB * NSEQ)

#define QK_SCALE 1.2011224087864498f   // sqrt(log2(e))

typedef __attribute__((ext_vector_type(8))) short short8;
typedef __attribute__((ext_vector_type(4))) float f32x4;

__device__ __forceinline__ float fast_exp2(float x) {
#if __has_builtin(__builtin_amdgcn_exp2f)
    return __builtin_amdgcn_exp2f(x);
#else
    return exp2f(x);
#endif
}

__device__ __forceinline__ unsigned short bf16_rne(float f) {
    unsigned u = __float_as_uint(f);
    u += 0x7fffu + ((u >> 16) & 1u);
    return (unsigned short)(u >> 16);
}

__device__ __forceinline__ short8 u4_to_s8(uint4 u) {
    union { uint4 u; short8 s; } c; c.u = u; return c.s;
}

#define AS3U(p) ((__attribute__((address_space(3))) unsigned int*)(p))
#define AS1U(p) ((const __attribute__((address_space(1))) unsigned int*)(p))

// ---------------------------------------------------------------------------
// Vt global layout is FRAGMENT-MAJOR: Vt_frag[b][jc][ct][lane] x 8 bf16,
// lane = q*16 + rit  holds  V[d = ct*16 + rit][j = jc*32 + q*8 .. +8].
// One (jc,ct) block = 64 lanes x 16 B = 1 KB. Per batch: 128*4 KB = 256 KB.
// This makes attn's LDS B-fragment reads base+lane*16 (conflict-free) and
// round staging one contiguous 64 KB DMA region.
// ---------------------------------------------------------------------------

// ---------------------------------------------------------------------------
// Kernel A: Qs/Ks = (x.wq/wk)*QK_SCALE, Vt_frag = bf16(x@Wv^T+bv)
// ---------------------------------------------------------------------------
__global__ __launch_bounds__(512) void qkv_kernel(
    const float* __restrict__ x, const float* __restrict__ Wv,
    const float* __restrict__ bv, const float* __restrict__ wq,
    const float* __restrict__ wk,
    float* __restrict__ Qs, float* __restrict__ Ks, unsigned short* __restrict__ Vt)
{
    __shared__ float x_lds[64 * 68];
    __shared__ float wvt[64 * 68];        // wvt[d*68+e] = Wv[e*64+d]
    __shared__ float wqk[128];
    __shared__ float bvl[64];
    __shared__ unsigned short vt_lds[64 * 72];   // [e][tok]

    const int t = threadIdx.x;
    const int tok0 = blockIdx.x * 64;

    #pragma unroll
    for (int r = 0; r < 2; ++r) {
        int f = t + 512 * r;
        int row = f >> 4, c4 = f & 15;
        float4 v = ((const float4*)(x + (size_t)(tok0 + row) * DK))[c4];
        *(float4*)&x_lds[row * 68 + c4 * 4] = v;
    }
    #pragma unroll
    for (int r = 0; r < 2; ++r) {
        int f = t + 512 * r;
        int e = f >> 4, c4 = f & 15;
        float4 v = ((const float4*)(Wv + e * DK))[c4];
        wvt[(c4 * 4 + 0) * 68 + e] = v.x;
        wvt[(c4 * 4 + 1) * 68 + e] = v.y;
        wvt[(c4 * 4 + 2) * 68 + e] = v.z;
        wvt[(c4 * 4 + 3) * 68 + e] = v.w;
    }
    if (t < 64) { wqk[t * 2] = wq[t]; wqk[t * 2 + 1] = wk[t]; bvl[t] = bv[t]; }
    __syncthreads();

    const int tok = t >> 3, oc = t & 7;
    const int e0 = oc * 8;
    float acc[8];
    #pragma unroll
    for (int ee = 0; ee < 8; ++ee) acc[ee] = bvl[e0 + ee];

    for (int d = 0; d < DK; d += 4) {
        float4 x4 = *(const float4*)&x_lds[tok * 68 + d];
        const float xs[4] = {x4.x, x4.y, x4.z, x4.w};
        #pragma unroll
        for (int dd = 0; dd < 4; ++dd) {
            float xv = xs[dd];
            const float4* wrow = (const float4*)&wvt[(d + dd) * 68 + e0];
            float4 wa = wrow[0], wb = wrow[1];
            acc[0] += xv * wa.x; acc[1] += xv * wa.y;
            acc[2] += xv * wa.z; acc[3] += xv * wa.w;
            acc[4] += xv * wb.x; acc[5] += xv * wb.y;
            acc[6] += xv * wb.z; acc[7] += xv * wb.w;
        }
    }
    #pragma unroll
    for (int k = 0; k < 8; ++k)
        vt_lds[(e0 + k) * 72 + tok] = bf16_rne(acc[k]);

    if (t < 128) {
        const int tk = t & 63;
        const int sel = (t >= 64);
        float a = 0.f;
        for (int d = 0; d < DK; ++d)
            a += x_lds[tk * 68 + d] * wqk[d * 2 + sel];
        (sel ? Ks : Qs)[tok0 + tk] = a * QK_SCALE;
    }
    __syncthreads();

    // fragment-major store: c = t>>6 (nl-group), d = t&63 -> contiguous lanes
    const int bb = tok0 >> 12, n0 = tok0 & 4095;
    {
        const int c = t >> 6, d = t & 63;
        uint4 v = *(const uint4*)((const char*)vt_lds + d * 144 + c * 16);  // 8 toks @ (d, c*8)
        const int jc   = (n0 >> 5) + (c >> 2);
        const int lane = (c & 3) * 16 + (d & 15);
        const int ct   = d >> 4;
        unsigned short* dst = Vt + ((((size_t)bb * 128 + jc) * 4 + ct) * 64 + lane) * 8;
        *(uint4*)dst = v;
    }
}

// ---------------------------------------------------------------------------
// Kernel B: MFMA attention + residual + layernorm.
// 256 blocks x 1024 threads (16 waves, 4/SIMD). XCD swizzle for L2 locality.
// V staged via global_load_lds from fragment-major Vt (contiguous 64 KB per
// round, double-buffered; buffers reuse the red-partials LDS region).
// B-fragment LDS reads are base+lane*16 -> conflict-free b128.
// LDS (floats): [0,4096) k | [4096,..) union{Vstage 2x32768 bf16, red 8x64x68} | dred 8x64
// ---------------------------------------------------------------------------
extern __shared__ float smem[];

__global__ __launch_bounds__(1024, 4) void attn_kernel(
    const float* __restrict__ x,
    const float* __restrict__ Qsg, const float* __restrict__ Ksg,
    const unsigned short* __restrict__ Vt,
    const float* __restrict__ gamma, const float* __restrict__ beta,
    float* __restrict__ out, int nrep)
{
    float* k_lds = smem;                          // 4096 floats
    unsigned short* vs = (unsigned short*)(smem + 4096);   // 2 x 32768 bf16 (128 KB)
    float* red   = smem + 4096;                   // 8 slots x 64 rows x 68 (post-loop reuse)
    float* dred  = smem + 4096 + 8 * 64 * 68;     // 8 x 64

    const int t    = threadIdx.x;
    const int B    = blockIdx.x;
    const int b    = (B & 7) >> 1;                         // batch <- XCD pair
    const int i0   = (((B >> 3) << 1) | (B & 1)) << 6;     // i-tile
    const int w    = t >> 6;
    const int lane = t & 63;
    const int rit  = lane & 15;
    const int q    = lane >> 4;
    const int rgrp = w >> 3;          // 0..1: 32-row group
    const int js   = w & 7;           // 0..7: 64-j piece within each round

    ((float4*)k_lds)[t] = ((const float4*)(Ksg + (size_t)b * 4096))[t];

    const float Qs0 = Qsg[b * 4096 + i0 + rgrp * 32 + rit];
    const float Qs1 = Qsg[b * 4096 + i0 + rgrp * 32 + 16 + rit];

    const short onebf = (short)0x3F80;
    const short8 vones = {onebf, onebf, onebf, onebf, onebf, onebf, onebf, onebf};

    const unsigned short* Vtb0 = Vt + (size_t)b * 262144;   // 128*4*64*8 shorts

    for (int rep = 0; rep < nrep; ++rep) {

    f32x4 acc[2][4] = {};
    f32x4 accd[2] = {};

    // ---- prologue: stage round 0 into buf 0 (4 contiguous 1 KB DMA rows/wave)
    #pragma unroll
    for (int i = 0; i < 4; ++i) {
        const int row = w + 16 * i;                 // (jc_local*4 + ct)
        const unsigned short* g = Vtb0 + row * 512 + lane * 8;
        unsigned short* l = vs + row * 512;         // wave-uniform base; DMA adds lane*16
#if __has_builtin(__builtin_amdgcn_global_load_lds)
        __builtin_amdgcn_global_load_lds(AS1U(g), AS3U(l), 16, 0, 0);
#else
        *(uint4*)(l + lane * 8) = *(const uint4*)g;
#endif
    }
    __syncthreads();   // k_lds + buf0 ready

    for (int r = 0; r < 8; ++r) {
        const int bf = r & 1;
        // ---- issue next round's DMA early (drained by end-of-round barrier)
        if (r < 7) {
            #pragma unroll
            for (int i = 0; i < 4; ++i) {
                const int row = w + 16 * i;
                const unsigned short* g = Vtb0 + (r + 1) * 32768 + row * 512 + lane * 8;
                unsigned short* l = vs + (bf ^ 1) * 32768 + row * 512;
#if __has_builtin(__builtin_amdgcn_global_load_lds)
                __builtin_amdgcn_global_load_lds(AS1U(g), AS3U(l), 16, 0, 0);
#else
                *(uint4*)(l + lane * 8) = *(const uint4*)g;
#endif
            }
        }

        // ---- compute: 2 MFMA k-steps from buf bf (conflict-free b128 reads)
        #pragma unroll
        for (int sl = 0; sl < 2; ++sl) {
            const int jcl = js * 2 + sl;                   // k-step within round
            const unsigned short* vf = vs + bf * 32768 + jcl * 2048 + lane * 8;
            uint4 bu0 = *(const uint4*)(vf);
            uint4 bu1 = *(const uint4*)(vf + 512);
            uint4 bu2 = *(const uint4*)(vf + 1024);
            uint4 bu3 = *(const uint4*)(vf + 1536);

            const float* kn = k_lds + r * 512 + jcl * 32 + q * 8;
            float4 ka = *(const float4*)(kn);
            float4 kb = *(const float4*)(kn + 4);
            float kv[8] = {ka.x, ka.y, ka.z, ka.w, kb.x, kb.y, kb.z, kb.w};

            float w0[8], w1[8];
            #pragma unroll
            for (int jj = 0; jj < 8; ++jj) {
                float d0 = Qs0 - kv[jj];
                float g0 = fast_exp2(-d0 * d0);
                float p0 = __builtin_fmaf(g0, 3.2552083e-4f, 7.8125e-3f);
                p0 = __builtin_fmaf(g0, p0, 0.125f);
                w0[jj] = __builtin_fmaf(g0, p0, 1.0f);   // exp(exp(-(Q-K)^2)/8)
                float d1 = Qs1 - kv[jj];
                float g1 = fast_exp2(-d1 * d1);
                float p1 = __builtin_fmaf(g1, 3.2552083e-4f, 7.8125e-3f);
                p1 = __builtin_fmaf(g1, p1, 0.125f);
                w1[jj] = __builtin_fmaf(g1, p1, 1.0f);
            }
            uint4 au0, au1;
            au0.x = __builtin_amdgcn_perm(__float_as_uint(w0[1]), __float_as_uint(w0[0]), 0x07060302u);
            au0.y = __builtin_amdgcn_perm(__float_as_uint(w0[3]), __float_as_uint(w0[2]), 0x07060302u);
            au0.z = __builtin_amdgcn_perm(__float_as_uint(w0[5]), __float_as_uint(w0[4]), 0x07060302u);
            au0.w = __builtin_amdgcn_perm(__float_as_uint(w0[7]), __float_as_uint(w0[6]), 0x07060302u);
            au1.x = __builtin_amdgcn_perm(__float_as_uint(w1[1]), __float_as_uint(w1[0]), 0x07060302u);
            au1.y = __builtin_amdgcn_perm(__float_as_uint(w1[3]), __float_as_uint(w1[2]), 0x07060302u);
            au1.z = __builtin_amdgcn_perm(__float_as_uint(w1[5]), __float_as_uint(w1[4]), 0x07060302u);
            au1.w = __builtin_amdgcn_perm(__float_as_uint(w1[7]), __float_as_uint(w1[6]), 0x07060302u);
            short8 a0 = u4_to_s8(au0);
            short8 a1 = u4_to_s8(au1);

            short8 b0 = u4_to_s8(bu0), b1 = u4_to_s8(bu1);
            short8 b2 = u4_to_s8(bu2), b3 = u4_to_s8(bu3);
            acc[0][0] = __builtin_amdgcn_mfma_f32_16x16x32_bf16(a0, b0, acc[0][0], 0, 0, 0);
            acc[0][1] = __builtin_amdgcn_mfma_f32_16x16x32_bf16(a0, b1, acc[0][1], 0, 0, 0);
            acc[0][2] = __builtin_amdgcn_mfma_f32_16x16x32_bf16(a0, b2, acc[0][2], 0, 0, 0);
            acc[0][3] = __builtin_amdgcn_mfma_f32_16x16x32_bf16(a0, b3, acc[0][3], 0, 0, 0);
            acc[1][0] = __builtin_amdgcn_mfma_f32_16x16x32_bf16(a1, b0, acc[1][0], 0, 0, 0);
            acc[1][1] = __builtin_amdgcn_mfma_f32_16x16x32_bf16(a1, b1, acc[1][1], 0, 0, 0);
            acc[1][2] = __builtin_amdgcn_mfma_f32_16x16x32_bf16(a1, b2, acc[1][2], 0, 0, 0);
            acc[1][3] = __builtin_amdgcn_mfma_f32_16x16x32_bf16(a1, b3, acc[1][3], 0, 0, 0);
            accd[0]   = __builtin_amdgcn_mfma_f32_16x16x32_bf16(a0, vones, accd[0], 0, 0, 0);
            accd[1]   = __builtin_amdgcn_mfma_f32_16x16x32_bf16(a1, vones, accd[1], 0, 0, 0);
        }
        __syncthreads();   // publishes next buf (DMA drained), protects buf reuse
    }

    // ---- write partials into red (reuses staging region; all reads done)
    {
        float* rbase = red + (size_t)js * (64 * 68);
        #pragma unroll
        for (int rt = 0; rt < 2; ++rt)
            #pragma unroll
            for (int ct = 0; ct < 4; ++ct)
                #pragma unroll
                for (int rg = 0; rg < 4; ++rg)
                    rbase[(rgrp * 32 + rt * 16 + q * 4 + rg) * 68 + ct * 16 + rit]
                        = acc[rt][ct][rg];
        if (rit == 0) {
            #pragma unroll
            for (int rt = 0; rt < 2; ++rt)
                #pragma unroll
                for (int rg = 0; rg < 4; ++rg)
                    dred[js * 64 + rgrp * 32 + rt * 16 + q * 4 + rg] = accd[rt][rg];
        }
    }
    __syncthreads();

    // ---- coalesced epilogue: thread = (row, 4 consecutive cols)
    {
        const int row = t >> 4, cg = t & 15, c0 = cg * 4;
        float dsum = 0.f;
        #pragma unroll
        for (int sl = 0; sl < 8; ++sl) dsum += dred[sl * 64 + row];
        const float inv = 1.0f / dsum;
        const size_t rowg = (size_t)(b * 4096 + i0 + row);

        float4 num = make_float4(0.f, 0.f, 0.f, 0.f);
        #pragma unroll
        for (int sl = 0; sl < 8; ++sl) {
            float4 r4 = *(const float4*)&red[(size_t)sl * (64 * 68) + row * 68 + c0];
            num.x += r4.x; num.y += r4.y; num.z += r4.z; num.w += r4.w;
        }
        const float4 x4 = *(const float4*)(x + rowg * 64 + c0);
        float4 h;
        h.x = num.x * inv + x4.x;
        h.y = num.y * inv + x4.y;
        h.z = num.z * inv + x4.z;
        h.w = num.w * inv + x4.w;

        float sm = h.x + h.y + h.z + h.w;
        float ss = h.x * h.x + h.y * h.y + h.z * h.z + h.w * h.w;
        #pragma unroll
        for (int m = 1; m < 16; m <<= 1) { sm += __shfl_xor(sm, m); ss += __shfl_xor(ss, m); }
        const float mu   = sm * 0.015625f;
        const float var  = ss * 0.015625f - mu * mu;
        const float rstd = rsqrtf(var + 1e-5f);

        const float4 g4 = *(const float4*)(gamma + c0);
        const float4 b4 = *(const float4*)(beta + c0);
        float4 o;
        o.x = (h.x - mu) * rstd * g4.x + b4.x;
        o.y = (h.y - mu) * rstd * g4.y + b4.y;
        o.z = (h.z - mu) * rstd * g4.z + b4.z;
        o.w = (h.w - mu) * rstd * g4.w + b4.w;
        *(float4*)(out + rowg * 64 + c0) = o;
    }
    __syncthreads();   // rep isolation
    }
}

// ---------------------------------------------------------------------------
extern "C" void kernel_launch(void* const* d_in, const int* in_sizes, int n_in,
                              void* d_out, int out_size, void* d_ws, size_t ws_size,
                              hipStream_t stream)
{
    const float* x     = (const float*)d_in[0];
    const float* Wv    = (const float*)d_in[1];
    const float* bv    = (const float*)d_in[2];
    const float* wq    = (const float*)d_in[3];
    const float* wk    = (const float*)d_in[4];
    const float* gamma = (const float*)d_in[5];
    const float* beta  = (const float*)d_in[6];
    float* out = (float*)d_out;

    float* Qs = (float*)d_ws;
    float* Ks = Qs + NTOK;
    unsigned short* Vt = (unsigned short*)(Ks + NTOK);

    // dynamic LDS: k 16384 + union(red 139264 / Vstage 131072) + dred 2048 = 157696 B
    const int attn_lds = 4096 * 4 + 8 * 64 * 68 * 4 + 8 * 64 * 4;
    hipFuncSetAttribute((const void*)attn_kernel,
                        hipFuncAttributeMaxDynamicSharedMemorySize, attn_lds);

    qkv_kernel<<<dim3(NTOK / 64), dim3(512), 0, stream>>>(x, Wv, bv, wq, wk, Qs, Ks, Vt);
    attn_kernel<<<dim3(NB * (NSEQ / 64)), dim3(1024), attn_lds, stream>>>(
        x, Qs, Ks, Vt, gamma, beta, out, 1);
}